// Round 1
// baseline (161.315 us; speedup 1.0000x reference)
//
#include <hip/hip_runtime.h>
#include <cmath>

#define BB 2
#define SS 2048
#define EE 512
#define HH 8
#define DD 64

typedef unsigned short u16t;
typedef __bf16 bf16x8 __attribute__((ext_vector_type(8)));
typedef float f32x4 __attribute__((ext_vector_type(4)));

__device__ __forceinline__ float bf2f(u16t u){
    union{unsigned int i; float f;} c; c.i = ((unsigned int)u)<<16; return c.f;
}
__device__ __forceinline__ u16t f2bf(float x){
    union{float f; unsigned int i;} c; c.f = x;
    return (u16t)((c.i + 0x7fffu + ((c.i>>16)&1u))>>16);
}
__device__ __forceinline__ float fast_tanh(float x){
    float e = __expf(2.f*x); return 1.f - 2.f/(e+1.f);
}
__device__ __forceinline__ float fast_atanh(float x){
    return 0.5f*__logf((1.f+x)/(1.f-x));
}
__device__ __forceinline__ f32x4 mfma16(bf16x8 a, bf16x8 b, f32x4 c){
    return __builtin_amdgcn_mfma_f32_16x16x32_bf16(a,b,c,0,0,0);
}

// ---------------- Kernel A1: logmap0 rows, fp32 -> bf16 tangent ----------------
__global__ __launch_bounds__(64) void k_logmap(const float* __restrict__ qp,
                                               const float* __restrict__ kp,
                                               const float* __restrict__ vp,
                                               u16t* __restrict__ Tlog){
    int bx = blockIdx.x;            // 0..12287
    int t = bx >> 12;               // /4096
    int row = bx & 4095;
    const float* src = (t==0 ? qp : (t==1 ? kp : vp)) + (size_t)row*EE;
    int tid = threadIdx.x;
    const float4* s4 = (const float4*)(src + tid*8);
    float4 a = s4[0], b = s4[1];
    float x[8] = {a.x,a.y,a.z,a.w,b.x,b.y,b.z,b.w};
    float p = 0.f;
    #pragma unroll
    for (int i=0;i<8;++i) p += x[i]*x[i];
    #pragma unroll
    for (int off=32; off>=1; off>>=1) p += __shfl_xor(p, off, 64);
    float n = sqrtf(fmaxf(p, 1e-12f));
    float f = fast_atanh(fminf(n, 1.0f-1e-5f)) / n;
    u16t yb[8];
    #pragma unroll
    for (int i=0;i<8;++i) yb[i] = f2bf(f*x[i]);
    uint4 o;
    o.x = (unsigned)yb[0] | ((unsigned)yb[1]<<16);
    o.y = (unsigned)yb[2] | ((unsigned)yb[3]<<16);
    o.z = (unsigned)yb[4] | ((unsigned)yb[5]<<16);
    o.w = (unsigned)yb[6] | ((unsigned)yb[7]<<16);
    *(uint4*)(Tlog + ((size_t)(t*4096+row)*EE + tid*8)) = o;
}

// ---------------- Kernel A2: W fp32 -> bf16 ----------------
__global__ __launch_bounds__(256) void k_cvtW(const float* __restrict__ Wq,
                                              const float* __restrict__ Wk,
                                              const float* __restrict__ Wv,
                                              u16t* __restrict__ Wb){
    int idx = (blockIdx.x*256 + threadIdx.x)*4;     // 3*512*512 total
    int t = idx >> 18;
    int off = idx & 262143;
    const float* W = (t==0 ? Wq : (t==1 ? Wk : Wv));
    float4 a = *(const float4*)(W + off);
    uint2 o;
    o.x = (unsigned)f2bf(a.x) | ((unsigned)f2bf(a.y)<<16);
    o.y = (unsigned)f2bf(a.z) | ((unsigned)f2bf(a.w)<<16);
    *(uint2*)(Wb + idx) = o;
}

// ---------------- Kernel B: U = Tlog @ W^T + b (MFMA GEMM) ----------------
__global__ __launch_bounds__(256) void k_proj(const u16t* __restrict__ Tlog,
                                              const u16t* __restrict__ Wb,
                                              const float* __restrict__ bq,
                                              const float* __restrict__ bk,
                                              const float* __restrict__ bv,
                                              float* __restrict__ U){
    __shared__ __align__(16) u16t Wl[64][72];
    int bx = blockIdx.x;                 // 3 * 64 * 8
    int t = bx >> 9; int rem = bx & 511;
    int m0 = (rem >> 3) << 6; int n0 = (rem & 7) << 6;
    int tid = threadIdx.x; int wv = tid>>6; int lane = tid&63;
    int l15 = lane & 15; int l4 = lane >> 4;
    const u16t* Tt = Tlog + (size_t)t*4096*EE;
    const u16t* Wt = Wb + (size_t)t*EE*EE;
    const float* bias = (t==0 ? bq : (t==1 ? bk : bv));
    f32x4 z = {0.f,0.f,0.f,0.f};
    f32x4 acc[4] = {z,z,z,z};
    int arow = m0 + 16*wv + l15;
    for (int ks=0; ks<8; ++ks){
        int k0 = ks*64;
        __syncthreads();
        {
            int rr = tid >> 2; int cc = (tid & 3) * 16;
            const uint4* g = (const uint4*)(Wt + (size_t)(n0+rr)*EE + k0 + cc);
            uint4 w0 = g[0], w1 = g[1];
            *(uint4*)&Wl[rr][cc]   = w0;
            *(uint4*)&Wl[rr][cc+8] = w1;
        }
        __syncthreads();
        bf16x8 a0 = *(const bf16x8*)(Tt + (size_t)arow*EE + k0 + l4*8);
        bf16x8 a1 = *(const bf16x8*)(Tt + (size_t)arow*EE + k0 + 32 + l4*8);
        #pragma unroll
        for (int f=0; f<4; ++f){
            bf16x8 b0 = *(const bf16x8*)&Wl[f*16+l15][l4*8];
            bf16x8 b1 = *(const bf16x8*)&Wl[f*16+l15][32+l4*8];
            acc[f] = mfma16(a0, b0, acc[f]);
            acc[f] = mfma16(a1, b1, acc[f]);
        }
    }
    float* Ut = U + (size_t)t*4096*EE;
    #pragma unroll
    for (int f=0; f<4; ++f){
        int col = n0 + f*16 + l15;
        float bs = bias[col];
        #pragma unroll
        for (int r=0; r<4; ++r){
            int row = m0 + 16*wv + l4*4 + r;
            Ut[(size_t)row*EE + col] = acc[f][r] + bs;
        }
    }
}

// ---------------- Kernel C: expmap0 + head split + norms ----------------
__global__ __launch_bounds__(64) void k_expmap_split(const float* __restrict__ U,
        u16t* __restrict__ Q, u16t* __restrict__ K, u16t* __restrict__ VL,
        float* __restrict__ qn2, float* __restrict__ kn2, float* __restrict__ lam1){
    int bx = blockIdx.x;            // 0..12287
    int t = bx >> 12;
    int row = bx & 4095;
    int b = row >> 11; int s = row & 2047;
    const float* u = U + ((size_t)t*4096 + row)*EE;
    int tid = threadIdx.x;
    const float4* s4 = (const float4*)(u + tid*8);
    float4 a = s4[0], bb = s4[1];
    float x[8] = {a.x,a.y,a.z,a.w,bb.x,bb.y,bb.z,bb.w};
    float p = 0.f;
    #pragma unroll
    for (int i=0;i<8;++i) p += x[i]*x[i];
    #pragma unroll
    for (int off=32; off>=1; off>>=1) p += __shfl_xor(p, off, 64);
    float n = sqrtf(fmaxf(p, 1e-12f));
    float f = fast_tanh(n)/n;
    float y[8]; u16t yb[8];
    float hp = 0.f;
    #pragma unroll
    for (int i=0;i<8;++i){
        yb[i] = f2bf(f*x[i]);
        y[i]  = bf2f(yb[i]);        // use rounded values for norms (consistency)
        hp += y[i]*y[i];
    }
    #pragma unroll
    for (int off=1; off<8; off<<=1) hp += __shfl_xor(hp, off, 64);
    int h = tid >> 3;
    size_t ih = (size_t)(b*HH + h)*SS + s;
    if (t == 0){
        uint4 o;
        o.x=(unsigned)yb[0]|((unsigned)yb[1]<<16); o.y=(unsigned)yb[2]|((unsigned)yb[3]<<16);
        o.z=(unsigned)yb[4]|((unsigned)yb[5]<<16); o.w=(unsigned)yb[6]|((unsigned)yb[7]<<16);
        *(uint4*)(Q + ih*DD + (tid&7)*8) = o;
        if ((tid&7)==0) qn2[ih] = hp;
    } else if (t == 1){
        uint4 o;
        o.x=(unsigned)yb[0]|((unsigned)yb[1]<<16); o.y=(unsigned)yb[2]|((unsigned)yb[3]<<16);
        o.z=(unsigned)yb[4]|((unsigned)yb[5]<<16); o.w=(unsigned)yb[6]|((unsigned)yb[7]<<16);
        *(uint4*)(K + ih*DD + (tid&7)*8) = o;
        if ((tid&7)==0) kn2[ih] = hp;
    } else {
        float lam = 2.f / fmaxf(1.f - hp, 1e-6f);
        u16t vb[8];
        #pragma unroll
        for (int i=0;i<8;++i) vb[i] = f2bf(y[i]*lam);
        uint4 o;
        o.x=(unsigned)vb[0]|((unsigned)vb[1]<<16); o.y=(unsigned)vb[2]|((unsigned)vb[3]<<16);
        o.z=(unsigned)vb[4]|((unsigned)vb[5]<<16); o.w=(unsigned)vb[6]|((unsigned)vb[7]<<16);
        *(uint4*)(VL + ih*DD + (tid&7)*8) = o;
        if ((tid&7)==0) lam1[ih] = lam - 1.f;
    }
}

// ---------------- Kernel D: fused causal hyperbolic attention ----------------
__global__ __launch_bounds__(256) void k_attn(const u16t* __restrict__ Q,
        const u16t* __restrict__ K, const u16t* __restrict__ VL,
        const float* __restrict__ qn2, const float* __restrict__ kn2,
        const float* __restrict__ lam1, const float* __restrict__ taup,
        const float* __restrict__ gammap, float* __restrict__ T2, float beta){
    __shared__ __align__(16) u16t Kt[64][72];
    __shared__ __align__(16) u16t Vt[64][72];   // transposed: Vt[d][kv]
    __shared__ __align__(16) u16t Wt[64][72];   // w stripes (per-wave private rows)
    __shared__ float kn2s[64], lam1s[64], qn2s[64];
    int bx = blockIdx.x;
    int bh = bx & 15;
    int qi = 31 - (bx >> 4);       // heavy tiles first
    int s0 = qi << 6;
    int tid = threadIdx.x; int wv = tid>>6; int lane = tid&63;
    int l15 = lane & 15; int l4 = lane >> 4;
    float tauexp = __expf(taup[0]);
    float gm = gammap[0];
    size_t base = (size_t)bh * SS;
    int qrow = s0 + 16*wv + l15;
    bf16x8 aQ0 = *(const bf16x8*)(Q + (base + qrow)*DD + l4*8);
    bf16x8 aQ1 = *(const bf16x8*)(Q + (base + qrow)*DD + 32 + l4*8);
    if (tid < 64) qn2s[tid] = qn2[base + s0 + tid];
    f32x4 z = {0.f,0.f,0.f,0.f};
    f32x4 num[4] = {z,z,z,z};
    float den[4] = {0.f,0.f,0.f,0.f};
    int mloc0 = 16*wv + l4*4;
    for (int jt=0; jt<=qi; ++jt){
        int kv0 = jt << 6;
        __syncthreads();
        {
            int rr = tid >> 2; int cc = (tid & 3) * 16;
            const uint4* gk = (const uint4*)(K + (base + kv0 + rr)*DD + cc);
            uint4 a0 = gk[0], a1 = gk[1];
            *(uint4*)&Kt[rr][cc]   = a0;
            *(uint4*)&Kt[rr][cc+8] = a1;
            const uint4* gv = (const uint4*)(VL + (base + kv0 + rr)*DD + cc);
            union { uint4 u[2]; u16t s[16]; } tv;
            tv.u[0] = gv[0]; tv.u[1] = gv[1];
            #pragma unroll
            for (int i=0;i<16;++i) Vt[cc+i][rr] = tv.s[i];
            if (tid < 64){
                kn2s[tid]  = kn2[base+kv0+tid];
                lam1s[tid] = lam1[base+kv0+tid];
            }
        }
        __syncthreads();
        f32x4 c[4] = {z,z,z,z};
        #pragma unroll
        for (int f=0; f<4; ++f){
            bf16x8 b0 = *(const bf16x8*)&Kt[f*16+l15][l4*8];
            bf16x8 b1 = *(const bf16x8*)&Kt[f*16+l15][32+l4*8];
            c[f] = mfma16(aQ0, b0, c[f]);
            c[f] = mfma16(aQ1, b1, c[f]);
        }
        bool diag = (jt == qi);
        #pragma unroll
        for (int f=0; f<4; ++f){
            int nl = f*16 + l15;
            float kv2 = kn2s[nl];
            float l1  = lam1s[nl];
            #pragma unroll
            for (int r=0; r<4; ++r){
                int ml = mloc0 + r;
                float qv = qn2s[ml];
                float sq  = fmaxf(qv + kv2 - 2.f*c[f][r], 0.f);
                float dnm = fmaxf((1.f-qv)*(1.f-kv2), 1e-6f);
                float rrho = fmaxf(2.f*sq/dnm, 1e-7f);
                float dist = __logf(1.f + rrho + sqrtf(rrho*(rrho+2.f)));
                float wval = __expf(gm - dist*tauexp);
                if (diag && (kv0+nl) > (s0+ml)) wval = 0.f;
                den[r] += wval * l1;
                Wt[ml][nl] = f2bf(wval);
            }
        }
        bf16x8 aW0 = *(const bf16x8*)&Wt[16*wv + l15][l4*8];
        bf16x8 aW1 = *(const bf16x8*)&Wt[16*wv + l15][32 + l4*8];
        #pragma unroll
        for (int f=0; f<4; ++f){
            bf16x8 b0 = *(const bf16x8*)&Vt[f*16+l15][l4*8];
            bf16x8 b1 = *(const bf16x8*)&Vt[f*16+l15][32+l4*8];
            num[f] = mfma16(aW0, b0, num[f]);
            num[f] = mfma16(aW1, b1, num[f]);
        }
    }
    // epilogue: den reduce, gyromidpoint + logmap (collapsed analytically)
    #pragma unroll
    for (int r=0; r<4; ++r){
        #pragma unroll
        for (int off=1; off<16; off<<=1) den[r] += __shfl_xor(den[r], off, 64);
    }
    float mv[4][4]; float mn2[4] = {0.f,0.f,0.f,0.f};
    #pragma unroll
    for (int f=0; f<4; ++f)
        #pragma unroll
        for (int r=0; r<4; ++r){
            mv[f][r] = num[f][r] / fmaxf(den[r], 1e-6f);
            mn2[r] += mv[f][r]*mv[f][r];
        }
    #pragma unroll
    for (int r=0; r<4; ++r){
        #pragma unroll
        for (int off=1; off<16; off<<=1) mn2[r] += __shfl_xor(mn2[r], off, 64);
    }
    int b = bh >> 3; int h = bh & 7;
    #pragma unroll
    for (int r=0; r<4; ++r){
        float mn = sqrtf(fmaxf(mn2[r], 1e-12f));
        float g = beta * 0.5f * fast_atanh(fminf(mn, 1.0f-1e-5f)) / mn;
        int ml = mloc0 + r;
        #pragma unroll
        for (int f=0; f<4; ++f){
            int nl = f*16 + l15;
            T2[((size_t)b*SS + s0 + ml)*EE + h*DD + nl] = g * mv[f][r];
        }
    }
}

// ---------------- Kernel E: final expmap0 ----------------
__global__ __launch_bounds__(64) void k_final(const float* __restrict__ T2,
                                              float* __restrict__ out){
    int row = blockIdx.x;
    int tid = threadIdx.x;
    const float* src = T2 + (size_t)row*EE;
    const float4* s4 = (const float4*)(src + tid*8);
    float4 a = s4[0], b = s4[1];
    float x[8] = {a.x,a.y,a.z,a.w,b.x,b.y,b.z,b.w};
    float p = 0.f;
    #pragma unroll
    for (int i=0;i<8;++i) p += x[i]*x[i];
    #pragma unroll
    for (int off=32; off>=1; off>>=1) p += __shfl_xor(p, off, 64);
    float n = sqrtf(fmaxf(p, 1e-12f));
    float f = fast_tanh(n)/n;
    float4 o0 = {f*x[0], f*x[1], f*x[2], f*x[3]};
    float4 o1 = {f*x[4], f*x[5], f*x[6], f*x[7]};
    float4* d4 = (float4*)(out + (size_t)row*EE + tid*8);
    d4[0] = o0; d4[1] = o1;
}

extern "C" void kernel_launch(void* const* d_in, const int* in_sizes, int n_in,
                              void* d_out, int out_size, void* d_ws, size_t ws_size,
                              hipStream_t stream) {
    const float* q_in  = (const float*)d_in[0];
    const float* k_in  = (const float*)d_in[1];
    const float* v_in  = (const float*)d_in[2];
    const float* Wq    = (const float*)d_in[3];
    const float* Wk    = (const float*)d_in[4];
    const float* Wv    = (const float*)d_in[5];
    const float* bq    = (const float*)d_in[6];
    const float* bk    = (const float*)d_in[7];
    const float* bv    = (const float*)d_in[8];
    const float* tau   = (const float*)d_in[9];
    const float* gamma = (const float*)d_in[10];
    float* out = (float*)d_out;

    char* ws = (char*)d_ws;
    u16t*  Tlog = (u16t*)(ws + 0);            // 12,582,912 B ; reused as T2 later
    u16t*  Wb   = (u16t*)(ws + 12582912);     //  1,572,864 B
    float* U    = (float*)(ws + 14155776);    // 25,165,824 B
    u16t*  Qb   = (u16t*)(ws + 39321600);     //  4,194,304 B
    u16t*  Kb   = (u16t*)(ws + 43515904);     //  4,194,304 B
    u16t*  VLb  = (u16t*)(ws + 47710208);     //  4,194,304 B
    float* qn2  = (float*)(ws + 51904512);    //    131,072 B
    float* kn2  = (float*)(ws + 52035584);    //    131,072 B
    float* lam1 = (float*)(ws + 52166656);    //    131,072 B
    float* T2   = (float*)(ws + 0);           // aliases Tlog (dead by then)

    // beta-concatenation ratio: exp(lbeta(E/2,1/2) - lbeta(D/2,1/2))
    double lb1 = std::lgamma(256.0) + std::lgamma(0.5) - std::lgamma(256.5);
    double lb2 = std::lgamma(32.0)  + std::lgamma(0.5) - std::lgamma(32.5);
    float beta = (float)std::exp(lb1 - lb2);

    k_logmap<<<12288, 64, 0, stream>>>(q_in, k_in, v_in, Tlog);
    k_cvtW<<<768, 256, 0, stream>>>(Wq, Wk, Wv, Wb);
    k_proj<<<1536, 256, 0, stream>>>(Tlog, Wb, bq, bk, bv, U);
    k_expmap_split<<<12288, 64, 0, stream>>>(U, Qb, Kb, VLb, qn2, kn2, lam1);
    k_attn<<<512, 256, 0, stream>>>(Qb, Kb, VLb, qn2, kn2, lam1, tau, gamma, T2, beta);
    k_final<<<4096, 64, 0, stream>>>(T2, out);
}

// Round 2
// 103.315 us; speedup vs baseline: 1.5614x; 1.5614x over previous
//
#include <hip/hip_runtime.h>
#include <cmath>

#define BB 2
#define SS 2048
#define EE 512
#define HH 8
#define DD 64

typedef unsigned short u16t;
typedef __bf16 bf16x8 __attribute__((ext_vector_type(8)));
typedef float f32x4 __attribute__((ext_vector_type(4)));

__device__ __forceinline__ float bf2f(u16t u){
    union{unsigned int i; float f;} c; c.i = ((unsigned int)u)<<16; return c.f;
}
__device__ __forceinline__ u16t f2bf(float x){
    union{float f; unsigned int i;} c; c.f = x;
    return (u16t)((c.i + 0x7fffu + ((c.i>>16)&1u))>>16);
}
__device__ __forceinline__ float fast_tanh(float x){
    float e = __expf(2.f*x); return 1.f - 2.f/(e+1.f);
}
__device__ __forceinline__ float fast_atanh(float x){
    return 0.5f*__logf((1.f+x)/(1.f-x));
}
__device__ __forceinline__ f32x4 mfma16(bf16x8 a, bf16x8 b, f32x4 c){
    return __builtin_amdgcn_mfma_f32_16x16x32_bf16(a,b,c,0,0,0);
}
// chunk index base for qi>=8 (chunks of 8 kv-tiles); totals 72 per bh
__device__ __forceinline__ int chunk_off(int qi){
    int g = qi >> 3;   // 1,2,3
    return (g==1) ? 2*(qi-8) : ((g==2) ? 16 + 3*(qi-16) : 40 + 4*(qi-24));
}

// ---------------- Kernel A1: logmap0 rows, fp32 -> bf16 tangent ----------------
__global__ __launch_bounds__(256) void k_logmap(const float* __restrict__ qp,
                                                const float* __restrict__ kp,
                                                const float* __restrict__ vp,
                                                u16t* __restrict__ Tlog){
    int gr = blockIdx.x*4 + (threadIdx.x>>6);   // 0..12287
    int t = gr >> 12;
    int row = gr & 4095;
    int lane = threadIdx.x & 63;
    const float* src = (t==0 ? qp : (t==1 ? kp : vp)) + (size_t)row*EE;
    const float4* s4 = (const float4*)(src + lane*8);
    float4 a = s4[0], b = s4[1];
    float x[8] = {a.x,a.y,a.z,a.w,b.x,b.y,b.z,b.w};
    float p = 0.f;
    #pragma unroll
    for (int i=0;i<8;++i) p += x[i]*x[i];
    #pragma unroll
    for (int off=32; off>=1; off>>=1) p += __shfl_xor(p, off, 64);
    float n = sqrtf(fmaxf(p, 1e-12f));
    float f = fast_atanh(fminf(n, 1.0f-1e-5f)) / n;
    u16t yb[8];
    #pragma unroll
    for (int i=0;i<8;++i) yb[i] = f2bf(f*x[i]);
    uint4 o;
    o.x = (unsigned)yb[0] | ((unsigned)yb[1]<<16);
    o.y = (unsigned)yb[2] | ((unsigned)yb[3]<<16);
    o.z = (unsigned)yb[4] | ((unsigned)yb[5]<<16);
    o.w = (unsigned)yb[6] | ((unsigned)yb[7]<<16);
    *(uint4*)(Tlog + ((size_t)(t*4096+row)*EE + lane*8)) = o;
}

// ---------------- Kernel A2: W fp32 -> bf16 ----------------
__global__ __launch_bounds__(256) void k_cvtW(const float* __restrict__ Wq,
                                              const float* __restrict__ Wk,
                                              const float* __restrict__ Wv,
                                              u16t* __restrict__ Wb){
    int idx = (blockIdx.x*256 + threadIdx.x)*4;     // 3*512*512 total
    int t = idx >> 18;
    int off = idx & 262143;
    const float* W = (t==0 ? Wq : (t==1 ? Wk : Wv));
    float4 a = *(const float4*)(W + off);
    uint2 o;
    o.x = (unsigned)f2bf(a.x) | ((unsigned)f2bf(a.y)<<16);
    o.y = (unsigned)f2bf(a.z) | ((unsigned)f2bf(a.w)<<16);
    *(uint2*)(Wb + idx) = o;
}

// ---------------- Kernel B: U = Tlog @ W^T + b (MFMA GEMM) ----------------
__global__ __launch_bounds__(256) void k_proj(const u16t* __restrict__ Tlog,
                                              const u16t* __restrict__ Wb,
                                              const float* __restrict__ bq,
                                              const float* __restrict__ bk,
                                              const float* __restrict__ bv,
                                              float* __restrict__ U){
    __shared__ __align__(16) u16t Wl[64][72];
    int bx = blockIdx.x;                 // 3 * 64 * 8
    int t = bx >> 9; int rem = bx & 511;
    int m0 = (rem >> 3) << 6; int n0 = (rem & 7) << 6;
    int tid = threadIdx.x; int wv = tid>>6; int lane = tid&63;
    int l15 = lane & 15; int l4 = lane >> 4;
    const u16t* Tt = Tlog + (size_t)t*4096*EE;
    const u16t* Wt = Wb + (size_t)t*EE*EE;
    const float* bias = (t==0 ? bq : (t==1 ? bk : bv));
    f32x4 z = {0.f,0.f,0.f,0.f};
    f32x4 acc[4] = {z,z,z,z};
    int arow = m0 + 16*wv + l15;
    for (int ks=0; ks<8; ++ks){
        int k0 = ks*64;
        __syncthreads();
        {
            int rr = tid >> 2; int cc = (tid & 3) * 16;
            const uint4* g = (const uint4*)(Wt + (size_t)(n0+rr)*EE + k0 + cc);
            uint4 w0 = g[0], w1 = g[1];
            *(uint4*)&Wl[rr][cc]   = w0;
            *(uint4*)&Wl[rr][cc+8] = w1;
        }
        __syncthreads();
        bf16x8 a0 = *(const bf16x8*)(Tt + (size_t)arow*EE + k0 + l4*8);
        bf16x8 a1 = *(const bf16x8*)(Tt + (size_t)arow*EE + k0 + 32 + l4*8);
        #pragma unroll
        for (int f=0; f<4; ++f){
            bf16x8 b0 = *(const bf16x8*)&Wl[f*16+l15][l4*8];
            bf16x8 b1 = *(const bf16x8*)&Wl[f*16+l15][32+l4*8];
            acc[f] = mfma16(a0, b0, acc[f]);
            acc[f] = mfma16(a1, b1, acc[f]);
        }
    }
    float* Ut = U + (size_t)t*4096*EE;
    #pragma unroll
    for (int f=0; f<4; ++f){
        int col = n0 + f*16 + l15;
        float bs = bias[col];
        #pragma unroll
        for (int r=0; r<4; ++r){
            int row = m0 + 16*wv + l4*4 + r;
            Ut[(size_t)row*EE + col] = acc[f][r] + bs;
        }
    }
}

// ---------------- Kernel C: expmap0 + head split + norms (V stored transposed) --
__global__ __launch_bounds__(256) void k_expmap_split(const float* __restrict__ U,
        u16t* __restrict__ Q, u16t* __restrict__ K, u16t* __restrict__ VT,
        float* __restrict__ qn2, float* __restrict__ kn2, float* __restrict__ lam1){
    int gr = blockIdx.x*4 + (threadIdx.x>>6);   // 0..12287
    int t = gr >> 12;
    int row = gr & 4095;
    int b = row >> 11; int s = row & 2047;
    int lane = threadIdx.x & 63;
    const float* u = U + ((size_t)t*4096 + row)*EE;
    const float4* s4 = (const float4*)(u + lane*8);
    float4 a = s4[0], bb = s4[1];
    float x[8] = {a.x,a.y,a.z,a.w,bb.x,bb.y,bb.z,bb.w};
    float p = 0.f;
    #pragma unroll
    for (int i=0;i<8;++i) p += x[i]*x[i];
    #pragma unroll
    for (int off=32; off>=1; off>>=1) p += __shfl_xor(p, off, 64);
    float n = sqrtf(fmaxf(p, 1e-12f));
    float f = fast_tanh(n)/n;
    float y[8]; u16t yb[8];
    float hp = 0.f;
    #pragma unroll
    for (int i=0;i<8;++i){
        yb[i] = f2bf(f*x[i]);
        y[i]  = bf2f(yb[i]);        // rounded values -> consistent norms
        hp += y[i]*y[i];
    }
    #pragma unroll
    for (int off=1; off<8; off<<=1) hp += __shfl_xor(hp, off, 64);
    hp = fminf(hp, 0.99999988f);    // guard: keep strictly below 1 for rcp path
    int h = lane >> 3;
    size_t ih = (size_t)(b*HH + h)*SS + s;
    if (t == 0){
        uint4 o;
        o.x=(unsigned)yb[0]|((unsigned)yb[1]<<16); o.y=(unsigned)yb[2]|((unsigned)yb[3]<<16);
        o.z=(unsigned)yb[4]|((unsigned)yb[5]<<16); o.w=(unsigned)yb[6]|((unsigned)yb[7]<<16);
        *(uint4*)(Q + ih*DD + (lane&7)*8) = o;
        if ((lane&7)==0) qn2[ih] = hp;
    } else if (t == 1){
        uint4 o;
        o.x=(unsigned)yb[0]|((unsigned)yb[1]<<16); o.y=(unsigned)yb[2]|((unsigned)yb[3]<<16);
        o.z=(unsigned)yb[4]|((unsigned)yb[5]<<16); o.w=(unsigned)yb[6]|((unsigned)yb[7]<<16);
        *(uint4*)(K + ih*DD + (lane&7)*8) = o;
        if ((lane&7)==0) kn2[ih] = hp;
    } else {
        float lam = 2.f / fmaxf(1.f - hp, 1e-6f);
        size_t bh = (size_t)(b*HH + h);
        int d0 = (lane&7)*8;
        #pragma unroll
        for (int i=0;i<8;++i)
            VT[(bh*DD + d0 + i)*SS + s] = f2bf(y[i]*lam);   // V^T, scaled by lambda
        if ((lane&7)==0) lam1[ih] = lam - 1.f;
    }
}

// ---------------- Kernel D: fused causal hyperbolic attention (kv-split) -------
__global__ __launch_bounds__(256,5) void k_attn(const u16t* __restrict__ Q,
        const u16t* __restrict__ K, const u16t* __restrict__ VT,
        const float* __restrict__ qn2, const float* __restrict__ kn2,
        const float* __restrict__ lam1, const float* __restrict__ taup,
        const float* __restrict__ gammap,
        float* __restrict__ pnum, float* __restrict__ pden,
        float* __restrict__ T2, float beta){
    __shared__ __align__(16) u16t Kt[64][72];
    __shared__ __align__(16) u16t Vt[64][72];   // V^T tile: [d][kv]
    __shared__ __align__(16) u16t Wt[64][72];   // per-wave-private w stripes
    __shared__ float kn2s[64], lam1s[64], qn2s[64];
    int bx = blockIdx.x;
    int bh = bx & 15;               // low bits -> per-bh XCD/L2 affinity
    int u = bx >> 4;                // 0..79: 48 full chunks first, then tails desc
    int qi, c0;
    if (u < 48){
        int g = u >> 3, r = u & 7;
        int qb = (g==0) ? 8 : ((g<3) ? 16 : 24);
        int cb = (g==0) ? 0 : ((g<3) ? (g-1) : (g-3));
        qi = qb + r; c0 = cb;
    } else {
        int p = u - 48;
        qi = (7 - (p>>2)) + ((p&3)<<3);
        c0 = qi >> 3;
    }
    int jt0 = c0 << 3;
    int jt1 = (u < 48) ? (jt0 + 8) : (qi + 1);
    int s0 = qi << 6;
    int tid = threadIdx.x; int wv = tid>>6; int lane = tid&63;
    int l15 = lane & 15; int l4 = lane >> 4;
    float tauexp = __expf(taup[0]);
    float gm2 = gammap[0] * 1.44269504088896340736f;  // gamma * log2(e)
    size_t base = (size_t)bh * SS;
    int qrow = s0 + 16*wv + l15;
    bf16x8 aQ0 = *(const bf16x8*)(Q + (base + qrow)*DD + l4*8);
    bf16x8 aQ1 = *(const bf16x8*)(Q + (base + qrow)*DD + 32 + l4*8);
    if (tid < 64) qn2s[tid] = qn2[base + s0 + tid];
    __syncthreads();
    int mloc0 = 16*wv + l4*4;
    float qv_[4], aq2_[4];
    #pragma unroll
    for (int r=0;r<4;++r){
        qv_[r]  = qn2s[mloc0+r];
        aq2_[r] = 2.f * __builtin_amdgcn_rcpf(fmaxf(1.f - qv_[r], 1e-6f));
    }
    f32x4 z4 = {0.f,0.f,0.f,0.f};
    f32x4 num[4] = {z4,z4,z4,z4};
    float den[4] = {0.f,0.f,0.f,0.f};
    int rr = tid >> 2; int cc = (tid & 3) << 4;
    for (int jt=jt0; jt<jt1; ++jt){
        int kv0 = jt << 6;
        {   // stage K rows and V^T rows (both row-major, vector writes)
            const uint4* gk = (const uint4*)(K + (base + kv0 + rr)*DD + cc);
            uint4 a0 = gk[0], a1 = gk[1];
            *(uint4*)&Kt[rr][cc]   = a0;
            *(uint4*)&Kt[rr][cc+8] = a1;
            const uint4* gv = (const uint4*)(VT + ((size_t)bh*DD + rr)*SS + kv0 + cc);
            uint4 b0 = gv[0], b1 = gv[1];
            *(uint4*)&Vt[rr][cc]   = b0;
            *(uint4*)&Vt[rr][cc+8] = b1;
            if (tid < 64){
                kn2s[tid]  = kn2[base+kv0+tid];
                lam1s[tid] = lam1[base+kv0+tid];
            }
        }
        __syncthreads();
        f32x4 c[4] = {z4,z4,z4,z4};
        #pragma unroll
        for (int f=0; f<4; ++f){
            bf16x8 b0 = *(const bf16x8*)&Kt[f*16+l15][l4*8];
            bf16x8 b1 = *(const bf16x8*)&Kt[f*16+l15][32+l4*8];
            c[f] = mfma16(aQ0, b0, c[f]);
            c[f] = mfma16(aQ1, b1, c[f]);
        }
        bool diag = (jt == qi);
        #pragma unroll
        for (int f=0; f<4; ++f){
            int nl = f*16 + l15;
            float kv2 = kn2s[nl];
            float l1  = lam1s[nl];
            float akf = __builtin_amdgcn_rcpf(fmaxf(1.f - kv2, 1e-6f));
            #pragma unroll
            for (int r=0; r<4; ++r){
                int ml = mloc0 + r;
                float sq  = fmaxf(fmaf(-2.f, c[f][r], qv_[r] + kv2), 0.f);
                float co  = fminf(aq2_[r]*akf, 2e6f);      // == 2/max(prod,1e-6)
                float rho = fmaxf(sq*co, 1e-7f);
                float tt  = fmaf(rho, rho, rho+rho);       // rho^2 + 2 rho
                float zz  = 1.f + rho + __builtin_amdgcn_sqrtf(tt);
                float L   = __builtin_amdgcn_logf(zz);     // log2
                float wval= __builtin_amdgcn_exp2f(fmaf(-tauexp, L, gm2));
                if (diag && (kv0+nl) > (s0+ml)) wval = 0.f;
                den[r] = fmaf(wval, l1, den[r]);
                Wt[ml][nl] = f2bf(wval);
            }
        }
        bf16x8 aW0 = *(const bf16x8*)&Wt[16*wv + l15][l4*8];
        bf16x8 aW1 = *(const bf16x8*)&Wt[16*wv + l15][32 + l4*8];
        #pragma unroll
        for (int f=0; f<4; ++f){
            bf16x8 b0 = *(const bf16x8*)&Vt[f*16+l15][l4*8];
            bf16x8 b1 = *(const bf16x8*)&Vt[f*16+l15][32+l4*8];
            num[f] = mfma16(aW0, b0, num[f]);
            num[f] = mfma16(aW1, b1, num[f]);
        }
        __syncthreads();
    }
    // reduce den across the 16-lane column groups
    #pragma unroll
    for (int r=0; r<4; ++r){
        #pragma unroll
        for (int off=1; off<16; off<<=1) den[r] += __shfl_xor(den[r], off, 64);
    }
    if (qi >= 8){
        // store partial (num, den) for the combine kernel
        size_t pidx = (size_t)bh*72 + chunk_off(qi) + c0;
        float* pn = pnum + pidx*4096;
        #pragma unroll
        for (int f=0; f<4; ++f){
            int nl = f*16 + l15;
            #pragma unroll
            for (int r=0; r<4; ++r)
                pn[(mloc0+r)*64 + nl] = num[f][r];
        }
        if (l15 == 0){
            #pragma unroll
            for (int r=0; r<4; ++r) pden[pidx*64 + mloc0 + r] = den[r];
        }
    } else {
        // single chunk: inline epilogue (gyromidpoint + logmap collapsed)
        float mv[4][4]; float mn2[4] = {0.f,0.f,0.f,0.f};
        #pragma unroll
        for (int f=0; f<4; ++f)
            #pragma unroll
            for (int r=0; r<4; ++r){
                mv[f][r] = num[f][r] / fmaxf(den[r], 1e-6f);
                mn2[r] += mv[f][r]*mv[f][r];
            }
        #pragma unroll
        for (int r=0; r<4; ++r){
            #pragma unroll
            for (int off=1; off<16; off<<=1) mn2[r] += __shfl_xor(mn2[r], off, 64);
        }
        int b = bh >> 3; int h = bh & 7;
        #pragma unroll
        for (int r=0; r<4; ++r){
            float mn = sqrtf(fmaxf(mn2[r], 1e-12f));
            float g = beta * 0.5f * fast_atanh(fminf(mn, 1.0f-1e-5f)) / mn;
            int ml = mloc0 + r;
            #pragma unroll
            for (int f=0; f<4; ++f){
                int nl = f*16 + l15;
                T2[((size_t)b*SS + s0 + ml)*EE + h*DD + nl] = g * mv[f][r];
            }
        }
    }
}

// ---------------- Kernel D2: combine partials + epilogue (qi >= 8) -------------
__global__ __launch_bounds__(256) void k_combine(const float* __restrict__ pnum,
        const float* __restrict__ pden, float* __restrict__ T2, float beta){
    int bx = blockIdx.x;              // 16 bh x 24 qtiles
    int bh = bx & 15; int qi = 8 + (bx >> 4);
    int nch = (qi >> 3) + 1;          // 2..4
    int t = threadIdx.x; int row = t >> 2; int qd = t & 3;
    size_t pb = (size_t)bh*72 + chunk_off(qi);
    float mv[16];
    #pragma unroll
    for (int i=0;i<16;++i) mv[i] = 0.f;
    float den = 0.f;
    for (int cc=0; cc<nch; ++cc){
        const float* pn = pnum + (pb+cc)*4096 + row*64 + qd*16;
        #pragma unroll
        for (int i=0;i<4;++i){
            float4 v = *(const float4*)(pn + i*4);
            mv[i*4+0]+=v.x; mv[i*4+1]+=v.y; mv[i*4+2]+=v.z; mv[i*4+3]+=v.w;
        }
        den += pden[(pb+cc)*64 + row];
    }
    float invd = 1.f / fmaxf(den, 1e-6f);
    float mn2 = 0.f;
    #pragma unroll
    for (int i=0;i<16;++i){ mv[i] *= invd; mn2 += mv[i]*mv[i]; }
    mn2 += __shfl_xor(mn2, 1, 64);
    mn2 += __shfl_xor(mn2, 2, 64);
    float mn = sqrtf(fmaxf(mn2, 1e-12f));
    float g = beta * 0.5f * fast_atanh(fminf(mn, 1.0f-1e-5f)) / mn;
    int b = bh >> 3, h = bh & 7;
    float* dst = T2 + ((size_t)b*SS + (qi<<6) + row)*EE + h*DD + qd*16;
    #pragma unroll
    for (int i=0;i<4;++i){
        float4 v = {g*mv[i*4+0], g*mv[i*4+1], g*mv[i*4+2], g*mv[i*4+3]};
        *(float4*)(dst + i*4) = v;
    }
}

// ---------------- Kernel E: final expmap0 ----------------
__global__ __launch_bounds__(256) void k_final(const float* __restrict__ T2,
                                               float* __restrict__ out){
    int row = blockIdx.x*4 + (threadIdx.x>>6);
    int lane = threadIdx.x & 63;
    const float* src = T2 + (size_t)row*EE;
    const float4* s4 = (const float4*)(src + lane*8);
    float4 a = s4[0], b = s4[1];
    float x[8] = {a.x,a.y,a.z,a.w,b.x,b.y,b.z,b.w};
    float p = 0.f;
    #pragma unroll
    for (int i=0;i<8;++i) p += x[i]*x[i];
    #pragma unroll
    for (int off=32; off>=1; off>>=1) p += __shfl_xor(p, off, 64);
    float n = sqrtf(fmaxf(p, 1e-12f));
    float f = fast_tanh(n)/n;
    float4 o0 = {f*x[0], f*x[1], f*x[2], f*x[3]};
    float4 o1 = {f*x[4], f*x[5], f*x[6], f*x[7]};
    float4* d4 = (float4*)(out + (size_t)row*EE + lane*8);
    d4[0] = o0; d4[1] = o1;
}

extern "C" void kernel_launch(void* const* d_in, const int* in_sizes, int n_in,
                              void* d_out, int out_size, void* d_ws, size_t ws_size,
                              hipStream_t stream) {
    const float* q_in  = (const float*)d_in[0];
    const float* k_in  = (const float*)d_in[1];
    const float* v_in  = (const float*)d_in[2];
    const float* Wq    = (const float*)d_in[3];
    const float* Wk    = (const float*)d_in[4];
    const float* Wv    = (const float*)d_in[5];
    const float* bq    = (const float*)d_in[6];
    const float* bk    = (const float*)d_in[7];
    const float* bv    = (const float*)d_in[8];
    const float* tau   = (const float*)d_in[9];
    const float* gamma = (const float*)d_in[10];
    float* out = (float*)d_out;

    char* ws = (char*)d_ws;
    // phase-1 buffers
    u16t*  Tlog = (u16t*)(ws + 0);            // 12,582,912 B (dead after k_proj)
    u16t*  Wb   = (u16t*)(ws + 12582912);     //  1,572,864 B (dead after k_proj)
    float* U    = (float*)(ws + 14155776);    // 25,165,824 B (dead after k_expmap_split)
    u16t*  Qb   = (u16t*)(ws + 39321600);     //  4,194,304 B
    u16t*  Kb   = (u16t*)(ws + 43515904);     //  4,194,304 B
    u16t*  VTb  = (u16t*)(ws + 47710208);     //  4,194,304 B  (V^T * lambda)
    float* qn2  = (float*)(ws + 51904512);    //    131,072 B
    float* kn2  = (float*)(ws + 52035584);    //    131,072 B
    float* lam1 = (float*)(ws + 52166656);    //    131,072 B -> ends 52,297,728
    // phase-2 overlays (first 39.3 MB is dead by the time k_attn runs)
    float* pnum = (float*)(ws + 0);           // 1152*4096*4 = 18,874,368 B
    float* pden = (float*)(ws + 18874368);    // 1152*64*4   =    294,912 B
    float* T2   = (float*)(ws + 19169280);    // 8,388,608 B -> ends 27,557,888

    // beta-concatenation ratio: exp(lbeta(E/2,1/2) - lbeta(D/2,1/2))
    double lb1 = std::lgamma(256.0) + std::lgamma(0.5) - std::lgamma(256.5);
    double lb2 = std::lgamma(32.0)  + std::lgamma(0.5) - std::lgamma(32.5);
    float beta = (float)std::exp(lb1 - lb2);

    k_logmap<<<3072, 256, 0, stream>>>(q_in, k_in, v_in, Tlog);
    k_cvtW<<<768, 256, 0, stream>>>(Wq, Wk, Wv, Wb);
    k_proj<<<1536, 256, 0, stream>>>(Tlog, Wb, bq, bk, bv, U);
    k_expmap_split<<<3072, 256, 0, stream>>>(U, Qb, Kb, VTb, qn2, kn2, lam1);
    k_attn<<<1280, 256, 0, stream>>>(Qb, Kb, VTb, qn2, kn2, lam1, tau, gamma,
                                     pnum, pden, T2, beta);
    k_combine<<<384, 256, 0, stream>>>(pnum, pden, T2, beta);
    k_final<<<1024, 256, 0, stream>>>(T2, out);
}

// Round 3
// 97.493 us; speedup vs baseline: 1.6546x; 1.0597x over previous
//
#include <hip/hip_runtime.h>
#include <cmath>

#define BB 2
#define SS 2048
#define EE 512
#define HH 8
#define DD 64

typedef unsigned short u16t;
typedef __bf16 bf16x8 __attribute__((ext_vector_type(8)));
typedef float f32x4 __attribute__((ext_vector_type(4)));

__device__ __forceinline__ float bf2f(u16t u){
    union{unsigned int i; float f;} c; c.i = ((unsigned int)u)<<16; return c.f;
}
__device__ __forceinline__ u16t f2bf(float x){
    union{float f; unsigned int i;} c; c.f = x;
    return (u16t)((c.i + 0x7fffu + ((c.i>>16)&1u))>>16);
}
__device__ __forceinline__ float fast_tanh(float x){
    float e = __expf(2.f*x); return 1.f - 2.f/(e+1.f);
}
__device__ __forceinline__ float fast_atanh(float x){
    return 0.5f*__logf((1.f+x)/(1.f-x));
}
__device__ __forceinline__ f32x4 mfma16(bf16x8 a, bf16x8 b, f32x4 c){
    return __builtin_amdgcn_mfma_f32_16x16x32_bf16(a,b,c,0,0,0);
}
// chunk index base for qi>=8 (chunks of 8 kv-tiles); totals 72 per bh
__device__ __forceinline__ int chunk_off(int qi){
    int g = qi >> 3;   // 1,2,3
    return (g==1) ? 2*(qi-8) : ((g==2) ? 16 + 3*(qi-16) : 40 + 4*(qi-24));
}

// ---------------- Kernel A: logmap0 rows (bf16 out) + W cvt, merged ------------
__global__ __launch_bounds__(256) void k_pre(const float* __restrict__ qp,
                                             const float* __restrict__ kp,
                                             const float* __restrict__ vp,
                                             u16t* __restrict__ Tlog,
                                             const float* __restrict__ Wq,
                                             const float* __restrict__ Wk,
                                             const float* __restrict__ Wv,
                                             u16t* __restrict__ Wb){
    int bx = blockIdx.x;
    if (bx < 3072){
        int gr = bx*4 + (threadIdx.x>>6);   // 0..12287
        int t = gr >> 12;
        int row = gr & 4095;
        int lane = threadIdx.x & 63;
        const float* src = (t==0 ? qp : (t==1 ? kp : vp)) + (size_t)row*EE;
        const float4* s4 = (const float4*)(src + lane*8);
        float4 a = s4[0], b = s4[1];
        float x[8] = {a.x,a.y,a.z,a.w,b.x,b.y,b.z,b.w};
        float p = 0.f;
        #pragma unroll
        for (int i=0;i<8;++i) p += x[i]*x[i];
        #pragma unroll
        for (int off=32; off>=1; off>>=1) p += __shfl_xor(p, off, 64);
        float n = sqrtf(fmaxf(p, 1e-12f));
        float f = fast_atanh(fminf(n, 1.0f-1e-5f)) / n;
        u16t yb[8];
        #pragma unroll
        for (int i=0;i<8;++i) yb[i] = f2bf(f*x[i]);
        uint4 o;
        o.x = (unsigned)yb[0] | ((unsigned)yb[1]<<16);
        o.y = (unsigned)yb[2] | ((unsigned)yb[3]<<16);
        o.z = (unsigned)yb[4] | ((unsigned)yb[5]<<16);
        o.w = (unsigned)yb[6] | ((unsigned)yb[7]<<16);
        *(uint4*)(Tlog + ((size_t)(t*4096+row)*EE + lane*8)) = o;
    } else {
        int idx = ((bx-3072)*256 + threadIdx.x)*4;     // 3*512*512 total
        int t = idx >> 18;
        int off = idx & 262143;
        const float* W = (t==0 ? Wq : (t==1 ? Wk : Wv));
        float4 a = *(const float4*)(W + off);
        uint2 o;
        o.x = (unsigned)f2bf(a.x) | ((unsigned)f2bf(a.y)<<16);
        o.y = (unsigned)f2bf(a.z) | ((unsigned)f2bf(a.w)<<16);
        *(uint2*)(Wb + idx) = o;
    }
}

// ---------------- Kernel B: U = Tlog @ W^T + b (MFMA GEMM, bf16 out) -----------
__global__ __launch_bounds__(256) void k_proj(const u16t* __restrict__ Tlog,
                                              const u16t* __restrict__ Wb,
                                              const float* __restrict__ bq,
                                              const float* __restrict__ bk,
                                              const float* __restrict__ bv,
                                              u16t* __restrict__ U){
    __shared__ __align__(16) u16t Wl[64][72];
    int bx = blockIdx.x;                 // 3 * 64 * 8
    int t = bx >> 9; int rem = bx & 511;
    int m0 = (rem >> 3) << 6; int n0 = (rem & 7) << 6;
    int tid = threadIdx.x; int wv = tid>>6; int lane = tid&63;
    int l15 = lane & 15; int l4 = lane >> 4;
    const u16t* Tt = Tlog + (size_t)t*4096*EE;
    const u16t* Wt = Wb + (size_t)t*EE*EE;
    const float* bias = (t==0 ? bq : (t==1 ? bk : bv));
    f32x4 z = {0.f,0.f,0.f,0.f};
    f32x4 acc[4] = {z,z,z,z};
    int arow = m0 + 16*wv + l15;
    for (int ks=0; ks<8; ++ks){
        int k0 = ks*64;
        __syncthreads();
        {
            int rr = tid >> 2; int cc = (tid & 3) * 16;
            const uint4* g = (const uint4*)(Wt + (size_t)(n0+rr)*EE + k0 + cc);
            uint4 w0 = g[0], w1 = g[1];
            *(uint4*)&Wl[rr][cc]   = w0;
            *(uint4*)&Wl[rr][cc+8] = w1;
        }
        __syncthreads();
        bf16x8 a0 = *(const bf16x8*)(Tt + (size_t)arow*EE + k0 + l4*8);
        bf16x8 a1 = *(const bf16x8*)(Tt + (size_t)arow*EE + k0 + 32 + l4*8);
        #pragma unroll
        for (int f=0; f<4; ++f){
            bf16x8 b0 = *(const bf16x8*)&Wl[f*16+l15][l4*8];
            bf16x8 b1 = *(const bf16x8*)&Wl[f*16+l15][32+l4*8];
            acc[f] = mfma16(a0, b0, acc[f]);
            acc[f] = mfma16(a1, b1, acc[f]);
        }
    }
    u16t* Ut = U + (size_t)t*4096*EE;
    #pragma unroll
    for (int f=0; f<4; ++f){
        int col = n0 + f*16 + l15;
        float bs = bias[col];
        #pragma unroll
        for (int r=0; r<4; ++r){
            int row = m0 + 16*wv + l4*4 + r;
            Ut[(size_t)row*EE + col] = f2bf(acc[f][r] + bs);
        }
    }
}

// ---------------- Kernel C: expmap0 + head split + norms (V stored transposed) --
__global__ __launch_bounds__(256) void k_expmap_split(const u16t* __restrict__ U,
        u16t* __restrict__ Q, u16t* __restrict__ K, u16t* __restrict__ VT,
        float* __restrict__ qn2, float* __restrict__ kn2, float* __restrict__ lam1){
    int gr = blockIdx.x*4 + (threadIdx.x>>6);   // 0..12287
    int t = gr >> 12;
    int row = gr & 4095;
    int b = row >> 11; int s = row & 2047;
    int lane = threadIdx.x & 63;
    const u16t* u = U + ((size_t)t*4096 + row)*EE;
    uint4 raw = *(const uint4*)(u + lane*8);
    const u16t* rs = (const u16t*)&raw;
    float x[8];
    #pragma unroll
    for (int i=0;i<8;++i) x[i] = bf2f(rs[i]);
    float p = 0.f;
    #pragma unroll
    for (int i=0;i<8;++i) p += x[i]*x[i];
    #pragma unroll
    for (int off=32; off>=1; off>>=1) p += __shfl_xor(p, off, 64);
    float n = sqrtf(fmaxf(p, 1e-12f));
    float f = fast_tanh(n)/n;
    float y[8]; u16t yb[8];
    float hp = 0.f;
    #pragma unroll
    for (int i=0;i<8;++i){
        yb[i] = f2bf(f*x[i]);
        y[i]  = bf2f(yb[i]);        // rounded values -> consistent norms
        hp += y[i]*y[i];
    }
    #pragma unroll
    for (int off=1; off<8; off<<=1) hp += __shfl_xor(hp, off, 64);
    hp = fminf(hp, 0.99999988f);    // guard: keep strictly below 1 for rcp path
    int h = lane >> 3;
    size_t ih = (size_t)(b*HH + h)*SS + s;
    if (t == 0){
        uint4 o;
        o.x=(unsigned)yb[0]|((unsigned)yb[1]<<16); o.y=(unsigned)yb[2]|((unsigned)yb[3]<<16);
        o.z=(unsigned)yb[4]|((unsigned)yb[5]<<16); o.w=(unsigned)yb[6]|((unsigned)yb[7]<<16);
        *(uint4*)(Q + ih*DD + (lane&7)*8) = o;
        if ((lane&7)==0) qn2[ih] = hp;
    } else if (t == 1){
        uint4 o;
        o.x=(unsigned)yb[0]|((unsigned)yb[1]<<16); o.y=(unsigned)yb[2]|((unsigned)yb[3]<<16);
        o.z=(unsigned)yb[4]|((unsigned)yb[5]<<16); o.w=(unsigned)yb[6]|((unsigned)yb[7]<<16);
        *(uint4*)(K + ih*DD + (lane&7)*8) = o;
        if ((lane&7)==0) kn2[ih] = hp;
    } else {
        float lam = 2.f / fmaxf(1.f - hp, 1e-6f);
        size_t bh = (size_t)(b*HH + h);
        int d0 = (lane&7)*8;
        #pragma unroll
        for (int i=0;i<8;++i)
            VT[(bh*DD + d0 + i)*SS + s] = f2bf(y[i]*lam);   // V^T, scaled by lambda
        if ((lane&7)==0) lam1[ih] = lam - 1.f;
    }
}

// ---------------- Kernel D: fused causal hyperbolic attention (kv-split) -------
// T14 async-STAGE: prefetch next kv-tile to regs while computing current tile.
__global__ __launch_bounds__(256,5) void k_attn(const u16t* __restrict__ Q,
        const u16t* __restrict__ K, const u16t* __restrict__ VT,
        const float* __restrict__ qn2, const float* __restrict__ kn2,
        const float* __restrict__ lam1, const float* __restrict__ taup,
        const float* __restrict__ gammap,
        float* __restrict__ pnum, float* __restrict__ pden,
        float* __restrict__ T2, float beta){
    __shared__ __align__(16) u16t Kt[64][72];
    __shared__ __align__(16) u16t Vt[64][72];   // V^T tile: [d][kv]
    __shared__ __align__(16) u16t Wt[64][72];   // per-wave-private w stripes
    __shared__ float kn2s[64], lam1s[64], qn2s[64];
    int bx = blockIdx.x;
    int bh = bx & 15;               // low bits -> per-bh XCD/L2 affinity
    int u = bx >> 4;                // 0..79: 48 full chunks first, then tails desc
    int qi, c0;
    if (u < 48){
        int g = u >> 3, r = u & 7;
        int qb = (g==0) ? 8 : ((g<3) ? 16 : 24);
        int cb = (g==0) ? 0 : ((g<3) ? (g-1) : (g-3));
        qi = qb + r; c0 = cb;
    } else {
        int p = u - 48;
        qi = (7 - (p>>2)) + ((p&3)<<3);
        c0 = qi >> 3;
    }
    int jt0 = c0 << 3;
    int jt1 = (u < 48) ? (jt0 + 8) : (qi + 1);
    int s0 = qi << 6;
    int tid = threadIdx.x; int wv = tid>>6; int lane = tid&63;
    int l15 = lane & 15; int l4 = lane >> 4;
    float tauexp = __expf(taup[0]);
    float gm2 = gammap[0] * 1.44269504088896340736f;  // gamma * log2(e)
    size_t base = (size_t)bh * SS;
    int qrow = s0 + 16*wv + l15;
    bf16x8 aQ0 = *(const bf16x8*)(Q + (base + qrow)*DD + l4*8);
    bf16x8 aQ1 = *(const bf16x8*)(Q + (base + qrow)*DD + 32 + l4*8);
    if (tid < 64) qn2s[tid] = qn2[base + s0 + tid];
    __syncthreads();
    int mloc0 = 16*wv + l4*4;
    float qv_[4], aq2_[4];
    #pragma unroll
    for (int r=0;r<4;++r){
        qv_[r]  = qn2s[mloc0+r];
        aq2_[r] = 2.f * __builtin_amdgcn_rcpf(fmaxf(1.f - qv_[r], 1e-6f));
    }
    f32x4 z4 = {0.f,0.f,0.f,0.f};
    f32x4 num[4] = {z4,z4,z4,z4};
    float den[4] = {0.f,0.f,0.f,0.f};
    int rr = tid >> 2; int cc = (tid & 3) << 4;
    // prefetch registers
    uint4 pka0, pka1, pva0, pva1; float pkn = 0.f, pl1 = 0.f;
    {   // prologue: load tile jt0
        int kv0 = jt0 << 6;
        const uint4* gk = (const uint4*)(K + (base + kv0 + rr)*DD + cc);
        pka0 = gk[0]; pka1 = gk[1];
        const uint4* gv = (const uint4*)(VT + ((size_t)bh*DD + rr)*SS + kv0 + cc);
        pva0 = gv[0]; pva1 = gv[1];
        if (tid < 64){ pkn = kn2[base+kv0+tid]; pl1 = lam1[base+kv0+tid]; }
    }
    for (int jt=jt0; jt<jt1; ++jt){
        // commit prefetched tile to LDS
        *(uint4*)&Kt[rr][cc]   = pka0;
        *(uint4*)&Kt[rr][cc+8] = pka1;
        *(uint4*)&Vt[rr][cc]   = pva0;
        *(uint4*)&Vt[rr][cc+8] = pva1;
        if (tid < 64){ kn2s[tid] = pkn; lam1s[tid] = pl1; }
        __syncthreads();
        // issue next tile's global loads (overlap with compute below)
        if (jt+1 < jt1){
            int kv0n = (jt+1) << 6;
            const uint4* gk = (const uint4*)(K + (base + kv0n + rr)*DD + cc);
            pka0 = gk[0]; pka1 = gk[1];
            const uint4* gv = (const uint4*)(VT + ((size_t)bh*DD + rr)*SS + kv0n + cc);
            pva0 = gv[0]; pva1 = gv[1];
            if (tid < 64){ pkn = kn2[base+kv0n+tid]; pl1 = lam1[base+kv0n+tid]; }
        }
        int kv0 = jt << 6;
        f32x4 c[4] = {z4,z4,z4,z4};
        #pragma unroll
        for (int f=0; f<4; ++f){
            bf16x8 b0 = *(const bf16x8*)&Kt[f*16+l15][l4*8];
            bf16x8 b1 = *(const bf16x8*)&Kt[f*16+l15][32+l4*8];
            c[f] = mfma16(aQ0, b0, c[f]);
            c[f] = mfma16(aQ1, b1, c[f]);
        }
        bool diag = (jt == qi);
        #pragma unroll
        for (int f=0; f<4; ++f){
            int nl = f*16 + l15;
            float kv2 = kn2s[nl];
            float l1  = lam1s[nl];
            float akf = __builtin_amdgcn_rcpf(fmaxf(1.f - kv2, 1e-6f));
            #pragma unroll
            for (int r=0; r<4; ++r){
                int ml = mloc0 + r;
                float sq  = fmaxf(fmaf(-2.f, c[f][r], qv_[r] + kv2), 0.f);
                float co  = fminf(aq2_[r]*akf, 2e6f);      // == 2/max(prod,1e-6)
                float rho = fmaxf(sq*co, 1e-7f);
                float tt  = fmaf(rho, rho, rho+rho);       // rho^2 + 2 rho
                float zz  = 1.f + rho + __builtin_amdgcn_sqrtf(tt);
                float L   = __builtin_amdgcn_logf(zz);     // log2
                float wval= __builtin_amdgcn_exp2f(fmaf(-tauexp, L, gm2));
                if (diag && (kv0+nl) > (s0+ml)) wval = 0.f;
                den[r] = fmaf(wval, l1, den[r]);
                Wt[ml][nl] = f2bf(wval);
            }
        }
        bf16x8 aW0 = *(const bf16x8*)&Wt[16*wv + l15][l4*8];
        bf16x8 aW1 = *(const bf16x8*)&Wt[16*wv + l15][32 + l4*8];
        #pragma unroll
        for (int f=0; f<4; ++f){
            bf16x8 b0 = *(const bf16x8*)&Vt[f*16+l15][l4*8];
            bf16x8 b1 = *(const bf16x8*)&Vt[f*16+l15][32+l4*8];
            num[f] = mfma16(aW0, b0, num[f]);
            num[f] = mfma16(aW1, b1, num[f]);
        }
        __syncthreads();
    }
    // reduce den across the 16-lane column groups
    #pragma unroll
    for (int r=0; r<4; ++r){
        #pragma unroll
        for (int off=1; off<16; off<<=1) den[r] += __shfl_xor(den[r], off, 64);
    }
    if (qi >= 8){
        // store partial (num, den) for the combine kernel
        size_t pidx = (size_t)bh*72 + chunk_off(qi) + c0;
        float* pn = pnum + pidx*4096;
        #pragma unroll
        for (int f=0; f<4; ++f){
            int nl = f*16 + l15;
            #pragma unroll
            for (int r=0; r<4; ++r)
                pn[(mloc0+r)*64 + nl] = num[f][r];
        }
        if (l15 == 0){
            #pragma unroll
            for (int r=0; r<4; ++r) pden[pidx*64 + mloc0 + r] = den[r];
        }
    } else {
        // single chunk: inline epilogue (gyromidpoint + logmap collapsed)
        float mv[4][4]; float mn2[4] = {0.f,0.f,0.f,0.f};
        #pragma unroll
        for (int f=0; f<4; ++f)
            #pragma unroll
            for (int r=0; r<4; ++r){
                mv[f][r] = num[f][r] / fmaxf(den[r], 1e-6f);
                mn2[r] += mv[f][r]*mv[f][r];
            }
        #pragma unroll
        for (int r=0; r<4; ++r){
            #pragma unroll
            for (int off=1; off<16; off<<=1) mn2[r] += __shfl_xor(mn2[r], off, 64);
        }
        int b = bh >> 3; int h = bh & 7;
        #pragma unroll
        for (int r=0; r<4; ++r){
            float mn = sqrtf(fmaxf(mn2[r], 1e-12f));
            float g = beta * 0.5f * fast_atanh(fminf(mn, 1.0f-1e-5f)) / mn;
            int ml = mloc0 + r;
            #pragma unroll
            for (int f=0; f<4; ++f){
                int nl = f*16 + l15;
                T2[((size_t)b*SS + s0 + ml)*EE + h*DD + nl] = g * mv[f][r];
            }
        }
    }
}

// ---------------- Kernel D2: combine partials + epilogue (qi >= 8) -------------
__global__ __launch_bounds__(256) void k_combine(const float* __restrict__ pnum,
        const float* __restrict__ pden, float* __restrict__ T2, float beta){
    int bx = blockIdx.x;              // 16 bh x 24 qtiles
    int bh = bx & 15; int qi = 8 + (bx >> 4);
    int nch = (qi >> 3) + 1;          // 2..4
    int t = threadIdx.x; int row = t >> 2; int qd = t & 3;
    size_t pb = (size_t)bh*72 + chunk_off(qi);
    float mv[16];
    #pragma unroll
    for (int i=0;i<16;++i) mv[i] = 0.f;
    float den = 0.f;
    for (int cc=0; cc<nch; ++cc){
        const float* pn = pnum + (pb+cc)*4096 + row*64 + qd*16;
        #pragma unroll
        for (int i=0;i<4;++i){
            float4 v = *(const float4*)(pn + i*4);
            mv[i*4+0]+=v.x; mv[i*4+1]+=v.y; mv[i*4+2]+=v.z; mv[i*4+3]+=v.w;
        }
        den += pden[(pb+cc)*64 + row];
    }
    float invd = 1.f / fmaxf(den, 1e-6f);
    float mn2 = 0.f;
    #pragma unroll
    for (int i=0;i<16;++i){ mv[i] *= invd; mn2 += mv[i]*mv[i]; }
    mn2 += __shfl_xor(mn2, 1, 64);
    mn2 += __shfl_xor(mn2, 2, 64);
    float mn = sqrtf(fmaxf(mn2, 1e-12f));
    float g = beta * 0.5f * fast_atanh(fminf(mn, 1.0f-1e-5f)) / mn;
    int b = bh >> 3, h = bh & 7;
    float* dst = T2 + ((size_t)b*SS + (qi<<6) + row)*EE + h*DD + qd*16;
    #pragma unroll
    for (int i=0;i<4;++i){
        float4 v = {g*mv[i*4+0], g*mv[i*4+1], g*mv[i*4+2], g*mv[i*4+3]};
        *(float4*)(dst + i*4) = v;
    }
}

// ---------------- Kernel E: final expmap0 ----------------
__global__ __launch_bounds__(256) void k_final(const float* __restrict__ T2,
                                               float* __restrict__ out){
    int row = blockIdx.x*4 + (threadIdx.x>>6);
    int lane = threadIdx.x & 63;
    const float* src = T2 + (size_t)row*EE;
    const float4* s4 = (const float4*)(src + lane*8);
    float4 a = s4[0], b = s4[1];
    float x[8] = {a.x,a.y,a.z,a.w,b.x,b.y,b.z,b.w};
    float p = 0.f;
    #pragma unroll
    for (int i=0;i<8;++i) p += x[i]*x[i];
    #pragma unroll
    for (int off=32; off>=1; off>>=1) p += __shfl_xor(p, off, 64);
    float n = sqrtf(fmaxf(p, 1e-12f));
    float f = fast_tanh(n)/n;
    float4 o0 = {f*x[0], f*x[1], f*x[2], f*x[3]};
    float4 o1 = {f*x[4], f*x[5], f*x[6], f*x[7]};
    float4* d4 = (float4*)(out + (size_t)row*EE + lane*8);
    d4[0] = o0; d4[1] = o1;
}

extern "C" void kernel_launch(void* const* d_in, const int* in_sizes, int n_in,
                              void* d_out, int out_size, void* d_ws, size_t ws_size,
                              hipStream_t stream) {
    const float* q_in  = (const float*)d_in[0];
    const float* k_in  = (const float*)d_in[1];
    const float* v_in  = (const float*)d_in[2];
    const float* Wq    = (const float*)d_in[3];
    const float* Wk    = (const float*)d_in[4];
    const float* Wv    = (const float*)d_in[5];
    const float* bq    = (const float*)d_in[6];
    const float* bk    = (const float*)d_in[7];
    const float* bv    = (const float*)d_in[8];
    const float* tau   = (const float*)d_in[9];
    const float* gamma = (const float*)d_in[10];
    float* out = (float*)d_out;

    char* ws = (char*)d_ws;
    // phase-1 buffers
    u16t*  Tlog = (u16t*)(ws + 0);            // 12,582,912 B (dead after k_proj)
    u16t*  Wb   = (u16t*)(ws + 12582912);     //  1,572,864 B (dead after k_proj)
    u16t*  Ub   = (u16t*)(ws + 14155776);     // 12,582,912 B bf16 (dead after k_expmap_split)
    u16t*  Qb   = (u16t*)(ws + 26738688);     //  4,194,304 B
    u16t*  Kb   = (u16t*)(ws + 30932992);     //  4,194,304 B
    u16t*  VTb  = (u16t*)(ws + 35127296);     //  4,194,304 B  (V^T * lambda)
    float* qn2  = (float*)(ws + 39321600);    //    131,072 B
    float* kn2  = (float*)(ws + 39452672);    //    131,072 B
    float* lam1 = (float*)(ws + 39583744);    //    131,072 B -> ends 39,714,816
    // phase-2 overlays: pnum/pden over dead Tlog/Wb/Ub; T2 after live buffers
    float* pnum = (float*)(ws + 0);           // 1152*4096*4 = 18,874,368 B
    float* pden = (float*)(ws + 18874368);    // 1152*64*4   =    294,912 B
    float* T2   = (float*)(ws + 39714816);    // 8,388,608 B -> ends 48,103,424

    // beta-concatenation ratio: exp(lbeta(E/2,1/2) - lbeta(D/2,1/2))
    double lb1 = std::lgamma(256.0) + std::lgamma(0.5) - std::lgamma(256.5);
    double lb2 = std::lgamma(32.0)  + std::lgamma(0.5) - std::lgamma(32.5);
    float beta = (float)std::exp(lb1 - lb2);

    k_pre<<<3840, 256, 0, stream>>>(q_in, k_in, v_in, Tlog, Wq, Wk, Wv, Wb);
    k_proj<<<1536, 256, 0, stream>>>(Tlog, Wb, bq, bk, bv, Ub);
    k_expmap_split<<<3072, 256, 0, stream>>>(Ub, Qb, Kb, VTb, qn2, kn2, lam1);
    k_attn<<<1280, 256, 0, stream>>>(Qb, Kb, VTb, qn2, kn2, lam1, tau, gamma,
                                     pnum, pden, T2, beta);
    k_combine<<<384, 256, 0, stream>>>(pnum, pden, T2, beta);
    k_final<<<1024, 256, 0, stream>>>(T2, out);
}